// Round 21
// baseline (116.004 us; speedup 1.0000x reference)
//
#include <hip/hip_runtime.h>
#include <hip/hip_bf16.h>
#include <type_traits>

using bf16x8_t = __attribute__((ext_vector_type(8))) __bf16;
using f32x4_t  = __attribute__((ext_vector_type(4))) float;

#define MFMA16(a, b, c) __builtin_amdgcn_mfma_f32_16x16x32_bf16((a), (b), (c), 0, 0, 0)

constexpr int BATCH   = 2;
constexpr int SEQ     = 2048;
constexpr int DMODEL  = 1024;
constexpr int DK      = 64;
constexpr int MTOT    = BATCH * SEQ;
// softmax in exp2 domain: Q pre-scaled at projection by 1/sqrt(64) * log2(e)
constexpr float SCL2 = 0.125f * 1.44269504088896f;

// ---- async global->LDS, 16B/lane; dest = wave-uniform base + lane*16 (m104) ----
typedef const __attribute__((address_space(1))) unsigned int ga_u32;
typedef __attribute__((address_space(3))) unsigned int ls_u32;
__device__ __forceinline__ void glds16(const void* g, void* l) {
    __builtin_amdgcn_global_load_lds((ga_u32*)g, (ls_u32*)l, 16, 0, 0);
}

// v_exp_f32 IS exp2
__device__ __forceinline__ float exp2_fast(float x) {
    float r;
    asm volatile("v_exp_f32 %0, %1" : "=v"(r) : "v"(x));
    return r;
}

__device__ __forceinline__ bf16x8_t cvt8(const float* __restrict__ p) {
    f32x4_t a = *(const f32x4_t*)p;
    f32x4_t b = *(const f32x4_t*)(p + 4);
    bf16x8_t r;
    r[0] = (__bf16)a[0]; r[1] = (__bf16)a[1]; r[2] = (__bf16)a[2]; r[3] = (__bf16)a[3];
    r[4] = (__bf16)b[0]; r[5] = (__bf16)b[1]; r[6] = (__bf16)b[2]; r[7] = (__bf16)b[3];
    return r;
}

// ---- fp32 -> bf16 convert for activations (y<3, 4M elems) and weights (y>=3, 1M) ----
__global__ __launch_bounds__(256) void cvt_all_kernel(
    const float* __restrict__ q, const float* __restrict__ k, const float* __restrict__ v,
    const float* __restrict__ w0, const float* __restrict__ w1,
    const float* __restrict__ w2, const float* __restrict__ w3,
    __bf16* __restrict__ dstA, __bf16* __restrict__ dstW)
{
    const int y = blockIdx.y;
    const float* src;
    __bf16* dst;
    if (y < 3) {
        const float* a[3] = {q, k, v};
        src = a[y];
        dst = dstA + (size_t)y * (MTOT * DMODEL);
    } else {
        if (blockIdx.x >= 512) return;
        const float* w[4] = {w0, w1, w2, w3};
        src = w[y - 3];
        dst = dstW + (size_t)(y - 3) * (DMODEL * DMODEL);
    }
    size_t i = ((size_t)blockIdx.x * 256 + threadIdx.x) * 8;
    *(bf16x8_t*)(dst + i) = cvt8(src + i);
}

// ================= GEMM: C[M,N] = A[M,K] * Bt[N,K]^T (R13, all-glds ring-3) =========
template<bool C_F32>
__device__ __forceinline__ void gemm_body(
    const __bf16* __restrict__ A, const __bf16* __restrict__ Bt,
    void* __restrict__ Cp, int m0, int n0, float cscale)
{
    constexpr int K = DMODEL, N = DMODEL;
    constexpr int NS = K / 32;                       // 32 K-steps
    __shared__ __align__(16) char smem[3][16384];    // per buf: A 8 KB + B 8 KB

    const int tid  = threadIdx.x;
    const int wave = tid >> 6, lane = tid & 63;
    const int wm = wave >> 1, wn = wave & 1;
    const int l15 = lane & 15, lhi = lane >> 4;

    auto stage = [&](int k0, int buf) {
        #pragma unroll
        for (int i = 0; i < 2; ++i) {
            int cbase = i * 256 + wave * 64;
            int slot = cbase + lane;
            int row = slot >> 2, c = slot & 3;
            int cs = (c + 4 - ((row >> 1) & 3)) & 3;
            glds16(A + (size_t)(m0 + row) * K + k0 + cs * 8, smem[buf] + (size_t)cbase * 16);
        }
        #pragma unroll
        for (int i = 0; i < 2; ++i) {
            int cbase = i * 256 + wave * 64;
            int slot = cbase + lane;
            int row = slot >> 2, c = slot & 3;
            int cs = (c + 4 - ((row >> 1) & 3)) & 3;
            glds16(Bt + (size_t)(n0 + row) * K + k0 + cs * 8,
                   smem[buf] + 8192 + (size_t)cbase * 16);
        }
    };

    f32x4_t acc[4][4] = {};

    auto mfma_step = [&](int buf) {
        const __bf16* a_ls = (const __bf16*)smem[buf];
        const __bf16* b_ls = (const __bf16*)(smem[buf] + 8192);
        bf16x8_t af[4], bfr[4];
        #pragma unroll
        for (int i = 0; i < 4; ++i) {
            int row = wm * 64 + i * 16 + l15;
            int lc = (lhi + (row >> 1)) & 3;
            af[i] = *(const bf16x8_t*)(a_ls + row * 32 + lc * 8);
        }
        #pragma unroll
        for (int j = 0; j < 4; ++j) {
            int row = wn * 64 + j * 16 + l15;
            int lc = (lhi + (row >> 1)) & 3;
            bfr[j] = *(const bf16x8_t*)(b_ls + row * 32 + lc * 8);
        }
        #pragma unroll
        for (int i = 0; i < 4; ++i)
            #pragma unroll
            for (int j = 0; j < 4; ++j)
                acc[i][j] = MFMA16(af[i], bfr[j], acc[i][j]);
    };

    // ---- prologue: 2 stages in flight ----
    stage(0, 0);
    stage(32, 1);

    // ---- main ring: t = 0..NS-3, stage t+2 each iter ----
    for (int t = 0; t < NS - 2; ++t) {
        asm volatile("s_waitcnt vmcnt(4)" ::: "memory");  // stage(t) landed; t+1 in flight
        __builtin_amdgcn_s_barrier();
        __builtin_amdgcn_sched_barrier(0);
        stage((t + 2) * 32, (t + 2) % 3);
        mfma_step(t % 3);
    }
    // ---- t = NS-2 (no stage issue) ----
    asm volatile("s_waitcnt vmcnt(4)" ::: "memory");
    __builtin_amdgcn_s_barrier();
    __builtin_amdgcn_sched_barrier(0);
    mfma_step((NS - 2) % 3);
    // ---- t = NS-1 (drain) ----
    asm volatile("s_waitcnt vmcnt(0)" ::: "memory");
    __builtin_amdgcn_s_barrier();
    __builtin_amdgcn_sched_barrier(0);
    mfma_step((NS - 1) % 3);

    // C/D layout (m89): col = lane&15, row = (lane>>4)*4 + reg
    #pragma unroll
    for (int i = 0; i < 4; ++i)
        #pragma unroll
        for (int j = 0; j < 4; ++j)
            #pragma unroll
            for (int r = 0; r < 4; ++r) {
                int row = m0 + wm * 64 + i * 16 + lhi * 4 + r;
                int col = n0 + wn * 64 + j * 16 + l15;
                float v = acc[i][j][r] * cscale;
                if constexpr (C_F32)
                    ((float*)Cp)[(size_t)row * N + col] = v;
                else
                    ((__bf16*)Cp)[(size_t)row * N + col] = (__bf16)v;
            }
}

// QKV projection: grid 768 blocks flat; XCD-swizzled (each XCD: 12 A-panels + 1 weight)
__global__ __launch_bounds__(256) void proj_qkv_kernel(
    const __bf16* __restrict__ act, const __bf16* __restrict__ wc,
    __bf16* __restrict__ oq, __bf16* __restrict__ ok, __bf16* __restrict__ ov)
{
    int lid = blockIdx.x + 8 * blockIdx.y + 256 * blockIdx.z;
    int nid = (lid & 7) * 96 + (lid >> 3);          // bijective: 768 = 8*96
    int z = nid >> 8, rem = nid & 255;
    int m0 = (rem >> 3) * 128, n0 = (rem & 7) * 128;

    const __bf16* A = act + (size_t)z * (MTOT * DMODEL);
    const __bf16* Bt = wc + (size_t)z * (DMODEL * DMODEL);
    __bf16* C; float cs;
    if (z == 0)      { C = oq; cs = SCL2; }
    else if (z == 1) { C = ok; cs = 1.0f; }
    else             { C = ov; cs = 1.0f; }
    gemm_body<false>(A, Bt, C, m0, n0, cs);
}

__global__ __launch_bounds__(256) void proj_out_kernel(
    const __bf16* __restrict__ ctx, const __bf16* __restrict__ woc, float* __restrict__ out)
{
    int lid = blockIdx.x + 8 * blockIdx.y;
    int nid = (lid & 7) * 32 + (lid >> 3);          // bijective: 256 = 8*32
    gemm_body<true>(ctx, woc, out, (nid >> 3) * 128, (nid & 7) * 128, 1.0f);
}

// ================= Flash attention (R21: 4-wave x 32 q-rows, reg-cached K/V frags) ===
// 512 blocks x 256 threads (4 waves), QBLK=128; each wave owns TWO 16-row sub-blocks
// processed back-to-back straight-line (R8 spill trigger was CONDITIONAL bodies; the
// unconditional dual-sub form is R10/R14-proven). K and V fragments are loaded into
// registers ONCE per tile (kf[2][4], vf[2][4], static indices) and reused by both
// sub-blocks -> DS b128 reads per 32 q-rows drop 36 -> 20 (R18 DS-pressure theory,
// 16x16-only mechanisms; 32x32 abandoned after R19/R20). No online max (R14);
// 1 __syncthreads/tile; K,V dbuf; proven swizzles/rotations throughout.
__global__ __launch_bounds__(256, 2) void attn_kernel(
    const __bf16* __restrict__ Qm, const __bf16* __restrict__ Km,
    const __bf16* __restrict__ Vm, __bf16* __restrict__ Om)
{
    constexpr int LDV = 72, LDP = 72;
    __shared__ __bf16 k_sh[2][64 * 64];     // dbuf; glds16, chunk xor (c^(row&7))
    __shared__ __bf16 v_sh[2][64 * LDV];    // dbuf; (d,kv) at d*72 + ((kv+8*(d>>3))&63)
    __shared__ __bf16 p_sh[4][16 * LDP];    // per-wave P (reused by both sub-blocks)

    const int tid  = threadIdx.x;
    const int wave = tid >> 6, lane = tid & 63;
    const int l15 = lane & 15, lhi = lane >> 4;

    int old = blockIdx.x + 16 * blockIdx.y;
    int nid = (old & 7) * 64 + (old >> 3);           // bijective: 512 = 8*64
    const int bh = nid >> 4, x = nid & 15;
    const int p = ((bh >> 1) & 1) ? 15 - x : x;      // 128-row q-tile depth, balanced
    const int q0 = p * 128;
    const int b = bh >> 4, h = bh & 15;

    const __bf16* Qb = Qm + (size_t)b * SEQ * DMODEL + h * DK;
    const __bf16* Kb = Km + (size_t)b * SEQ * DMODEL + h * DK;
    const __bf16* Vb = Vm + (size_t)b * SEQ * DMODEL + h * DK;

    const int qw0 = q0 + wave * 32;   // wave's rows: [qw0, qw0+16) and [qw0+16, qw0+32)

    // Q fragments (A layout: row = lane&15, k = (lane>>4)*8 + j); pre-scaled by SCL2
    bf16x8_t qf[2][2];
    #pragma unroll
    for (int s = 0; s < 2; ++s) {
        const __bf16* qp = Qb + (size_t)(qw0 + s * 16 + l15) * DMODEL + lhi * 8;
        qf[s][0] = *(const bf16x8_t*)qp;
        qf[s][1] = *(const bf16x8_t*)(qp + 32);
    }
    bf16x8_t onesf;
    #pragma unroll
    for (int j = 0; j < 8; ++j) onesf[j] = (__bf16)1.0f;

    f32x4_t acc[2][4] = {};
    f32x4_t acc_l[2] = {};   // row sums via ones-MFMA (replicated over l15)

    // ---- staging helpers (256 threads: two 16B K-chunks / two bf16x8 V-chunks) ----
    const int vrow = tid >> 3, vgrp = tid & 7;       // V rows vrow, vrow+32
    bf16x8_t vreg0, vreg1;

    auto stageK = [&](int kv0, int buf) {
        #pragma unroll
        for (int i = 0; i < 2; ++i) {
            int slot = tid + i * 256;
            int row = slot >> 3, c = (slot & 7) ^ (row & 7);
            glds16(Kb + (size_t)(kv0 + row) * DMODEL + c * 8,
                   (char*)k_sh[buf] + (size_t)slot * 16);
        }
    };
    auto loadV = [&](int kv0) {
        vreg0 = *(const bf16x8_t*)(Vb + (size_t)(kv0 + vrow) * DMODEL + vgrp * 8);
        vreg1 = *(const bf16x8_t*)(Vb + (size_t)(kv0 + 32 + vrow) * DMODEL + vgrp * 8);
    };
    auto writeV = [&](int buf) {
        int sh0 = (vrow + vgrp * 8) & 63;
        #pragma unroll
        for (int j = 0; j < 8; ++j) v_sh[buf][(vgrp * 8 + j) * LDV + sh0] = vreg0[j];
        int sh1 = (vrow + 32 + vgrp * 8) & 63;
        #pragma unroll
        for (int j = 0; j < 8; ++j) v_sh[buf][(vgrp * 8 + j) * LDV + sh1] = vreg1[j];
    };

    auto body = [&](auto needmask_c, int kv0, int cur) {
        constexpr bool NEEDMASK = decltype(needmask_c)::value;
        const __bf16* ks_buf = k_sh[cur];
        const __bf16* vs_buf = v_sh[cur];

        // ---- load K and V fragments ONCE (shared by both sub-blocks) ----
        bf16x8_t kf[2][4], vf[2][4];
        #pragma unroll
        for (int ks = 0; ks < 2; ++ks)
            #pragma unroll
            for (int n = 0; n < 4; ++n) {
                int row = n * 16 + l15;
                kf[ks][n] = *(const bf16x8_t*)(ks_buf + row * 64 + (((ks * 4 + lhi) ^ (row & 7)) * 8));
                int d = n * 16 + l15;
                int rot = (ks * 32 + lhi * 8 + ((d >> 3) << 3)) & 63;
                vf[ks][n] = *(const bf16x8_t*)(vs_buf + d * LDV + rot);
            }

        // ---- two 16-row sub-blocks, straight-line ----
        #pragma unroll
        for (int s = 0; s < 2; ++s) {
            // S = Q K^T (exp2 domain via pre-scaled Q)
            f32x4_t sf[4] = {};
            __builtin_amdgcn_s_setprio(1);
            #pragma unroll
            for (int ks = 0; ks < 2; ++ks)
                #pragma unroll
                for (int n = 0; n < 4; ++n)
                    sf[n] = MFMA16(qf[s][ks], kf[ks][n], sf[n]);
            __builtin_amdgcn_s_setprio(0);

            // P = exp2(S) with diag mask; write rotated to per-wave LDS
            const int qrb = qw0 + s * 16 + lhi * 4;
            #pragma unroll
            for (int r = 0; r < 4; ++r)
                #pragma unroll
                for (int n = 0; n < 4; ++n) {
                    float sv = sf[n][r];
                    if constexpr (NEEDMASK)
                        if (kv0 + n * 16 + l15 > qrb + r) sv = -1.0e30f;
                    p_sh[wave][(lhi * 4 + r) * LDP + ((n * 16 + l15 + ((lhi >> 1) << 3)) & 63)]
                        = (__bf16)exp2_fast(sv);
                }

            // ctx += P V ; l += P * ones (same-wave in-order LDS round trip)
            __builtin_amdgcn_s_setprio(1);
            #pragma unroll
            for (int ks = 0; ks < 2; ++ks) {
                bf16x8_t pa = *(const bf16x8_t*)(
                    &p_sh[wave][l15 * LDP + ((ks * 32 + lhi * 8 + ((l15 >> 3) << 3)) & 63)]);
                acc_l[s] = MFMA16(pa, onesf, acc_l[s]);
                #pragma unroll
                for (int n = 0; n < 4; ++n)
                    acc[s][n] = MFMA16(pa, vf[ks][n], acc[s][n]);
            }
            __builtin_amdgcn_s_setprio(0);
        }
    };

    // ---- prologue: stage tile 0 into buf 0 ----
    stageK(0, 0);
    loadV(0);
    writeV(0);           // compiler waits vmcnt for vregs
    __syncthreads();     // K glds + V ds_writes drained

    // ---- main loop: tiles 0..2p-1 provably unmasked for ALL waves; 1 barrier/tile ----
    for (int t = 0; t < 2 * p; ++t) {
        stageK((t + 1) * 64, (t & 1) ^ 1);   // async prefetch into other K buf
        loadV((t + 1) * 64);                 // global->reg, waits during body
        body(std::integral_constant<bool, false>{}, t * 64, t & 1);
        writeV((t & 1) ^ 1);                 // other V buf; no reader this tile
        __syncthreads();                     // drains everything; swap
    }
    // ---- diagonal tiles 2p (prefetch 2p+1), then 2p+1 ----
    {
        const int t = 2 * p;
        stageK((t + 1) * 64, (t & 1) ^ 1);
        loadV((t + 1) * 64);
        body(std::integral_constant<bool, true>{}, t * 64, t & 1);
        writeV((t & 1) ^ 1);
        __syncthreads();
        body(std::integral_constant<bool, true>{}, (t + 1) * 64, (t + 1) & 1);
    }

    // ---- epilogue ----
    __bf16* Ob = Om + (size_t)b * SEQ * DMODEL + h * DK;
    #pragma unroll
    for (int s = 0; s < 2; ++s)
        #pragma unroll
        for (int n = 0; n < 4; ++n)
            #pragma unroll
            for (int r = 0; r < 4; ++r) {
                int row = qw0 + s * 16 + lhi * 4 + r;
                Ob[(size_t)row * DMODEL + n * 16 + l15] = (__bf16)(acc[s][n][r] / acc_l[s][r]);
            }
}

// ================= launch ============================================================
extern "C" void kernel_launch(void* const* d_in, const int* in_sizes, int n_in,
                              void* d_out, int out_size, void* d_ws, size_t ws_size,
                              hipStream_t stream)
{
    const float* q  = (const float*)d_in[0];
    const float* k  = (const float*)d_in[1];
    const float* v  = (const float*)d_in[2];
    const float* wq = (const float*)d_in[4];
    const float* wk = (const float*)d_in[5];
    const float* wv = (const float*)d_in[6];
    const float* wo = (const float*)d_in[7];
    float* out = (float*)d_out;

    const size_t mat = (size_t)MTOT * DMODEL;        // 4M elems
    __bf16* Qw = (__bf16*)d_ws;                      // 8 MB each
    __bf16* Kw = Qw + mat;
    __bf16* Vw = Kw + mat;
    __bf16* Cw = Vw + mat;
    __bf16* Wc = Cw + mat;                           // 4 x 2MB bf16 weights
    __bf16* Aw = Wc + 4 * (size_t)(DMODEL * DMODEL); // 3 x 8MB bf16 activations

    dim3 blk(256);
    cvt_all_kernel<<<dim3(2048, 7), blk, 0, stream>>>(q, k, v, wq, wk, wv, wo, Aw, Wc);
    proj_qkv_kernel<<<dim3(8, 32, 3), blk, 0, stream>>>(Aw, Wc, Qw, Kw, Vw);
    attn_kernel<<<dim3(16, 32), blk, 0, stream>>>(Qw, Kw, Vw, Cw);
    proj_out_kernel<<<dim3(8, 32), blk, 0, stream>>>(Cw, Wc + 3 * DMODEL * DMODEL, out);
}

// Round 22
// 110.199 us; speedup vs baseline: 1.0527x; 1.0527x over previous
//
#include <hip/hip_runtime.h>
#include <hip/hip_bf16.h>
#include <type_traits>

using bf16x8_t = __attribute__((ext_vector_type(8))) __bf16;
using f32x4_t  = __attribute__((ext_vector_type(4))) float;

#define MFMA16(a, b, c) __builtin_amdgcn_mfma_f32_16x16x32_bf16((a), (b), (c), 0, 0, 0)

constexpr int BATCH   = 2;
constexpr int SEQ     = 2048;
constexpr int DMODEL  = 1024;
constexpr int DK      = 64;
constexpr int MTOT    = BATCH * SEQ;
// softmax in exp2 domain: Q pre-scaled at projection by 1/sqrt(64) * log2(e)
constexpr float SCL2 = 0.125f * 1.44269504088896f;

// ---- async global->LDS, 16B/lane; dest = wave-uniform base + lane*16 (m104) ----
typedef const __attribute__((address_space(1))) unsigned int ga_u32;
typedef __attribute__((address_space(3))) unsigned int ls_u32;
__device__ __forceinline__ void glds16(const void* g, void* l) {
    __builtin_amdgcn_global_load_lds((ga_u32*)g, (ls_u32*)l, 16, 0, 0);
}

// v_exp_f32 IS exp2
__device__ __forceinline__ float exp2_fast(float x) {
    float r;
    asm volatile("v_exp_f32 %0, %1" : "=v"(r) : "v"(x));
    return r;
}

__device__ __forceinline__ bf16x8_t cvt8(const float* __restrict__ p) {
    f32x4_t a = *(const f32x4_t*)p;
    f32x4_t b = *(const f32x4_t*)(p + 4);
    bf16x8_t r;
    r[0] = (__bf16)a[0]; r[1] = (__bf16)a[1]; r[2] = (__bf16)a[2]; r[3] = (__bf16)a[3];
    r[4] = (__bf16)b[0]; r[5] = (__bf16)b[1]; r[6] = (__bf16)b[2]; r[7] = (__bf16)b[3];
    return r;
}

// ---- fp32 -> bf16 convert for activations (y<3, 4M elems) and weights (y>=3, 1M) ----
__global__ __launch_bounds__(256) void cvt_all_kernel(
    const float* __restrict__ q, const float* __restrict__ k, const float* __restrict__ v,
    const float* __restrict__ w0, const float* __restrict__ w1,
    const float* __restrict__ w2, const float* __restrict__ w3,
    __bf16* __restrict__ dstA, __bf16* __restrict__ dstW)
{
    const int y = blockIdx.y;
    const float* src;
    __bf16* dst;
    if (y < 3) {
        const float* a[3] = {q, k, v};
        src = a[y];
        dst = dstA + (size_t)y * (MTOT * DMODEL);
    } else {
        if (blockIdx.x >= 512) return;
        const float* w[4] = {w0, w1, w2, w3};
        src = w[y - 3];
        dst = dstW + (size_t)(y - 3) * (DMODEL * DMODEL);
    }
    size_t i = ((size_t)blockIdx.x * 256 + threadIdx.x) * 8;
    *(bf16x8_t*)(dst + i) = cvt8(src + i);
}

// ================= GEMM: C[M,N] = A[M,K] * Bt[N,K]^T (R13, all-glds ring-3) =========
template<bool C_F32>
__device__ __forceinline__ void gemm_body(
    const __bf16* __restrict__ A, const __bf16* __restrict__ Bt,
    void* __restrict__ Cp, int m0, int n0, float cscale)
{
    constexpr int K = DMODEL, N = DMODEL;
    constexpr int NS = K / 32;                       // 32 K-steps
    __shared__ __align__(16) char smem[3][16384];    // per buf: A 8 KB + B 8 KB

    const int tid  = threadIdx.x;
    const int wave = tid >> 6, lane = tid & 63;
    const int wm = wave >> 1, wn = wave & 1;
    const int l15 = lane & 15, lhi = lane >> 4;

    auto stage = [&](int k0, int buf) {
        #pragma unroll
        for (int i = 0; i < 2; ++i) {
            int cbase = i * 256 + wave * 64;
            int slot = cbase + lane;
            int row = slot >> 2, c = slot & 3;
            int cs = (c + 4 - ((row >> 1) & 3)) & 3;
            glds16(A + (size_t)(m0 + row) * K + k0 + cs * 8, smem[buf] + (size_t)cbase * 16);
        }
        #pragma unroll
        for (int i = 0; i < 2; ++i) {
            int cbase = i * 256 + wave * 64;
            int slot = cbase + lane;
            int row = slot >> 2, c = slot & 3;
            int cs = (c + 4 - ((row >> 1) & 3)) & 3;
            glds16(Bt + (size_t)(n0 + row) * K + k0 + cs * 8,
                   smem[buf] + 8192 + (size_t)cbase * 16);
        }
    };

    f32x4_t acc[4][4] = {};

    auto mfma_step = [&](int buf) {
        const __bf16* a_ls = (const __bf16*)smem[buf];
        const __bf16* b_ls = (const __bf16*)(smem[buf] + 8192);
        bf16x8_t af[4], bfr[4];
        #pragma unroll
        for (int i = 0; i < 4; ++i) {
            int row = wm * 64 + i * 16 + l15;
            int lc = (lhi + (row >> 1)) & 3;
            af[i] = *(const bf16x8_t*)(a_ls + row * 32 + lc * 8);
        }
        #pragma unroll
        for (int j = 0; j < 4; ++j) {
            int row = wn * 64 + j * 16 + l15;
            int lc = (lhi + (row >> 1)) & 3;
            bfr[j] = *(const bf16x8_t*)(b_ls + row * 32 + lc * 8);
        }
        #pragma unroll
        for (int i = 0; i < 4; ++i)
            #pragma unroll
            for (int j = 0; j < 4; ++j)
                acc[i][j] = MFMA16(af[i], bfr[j], acc[i][j]);
    };

    // ---- prologue: 2 stages in flight ----
    stage(0, 0);
    stage(32, 1);

    // ---- main ring: t = 0..NS-3, stage t+2 each iter ----
    for (int t = 0; t < NS - 2; ++t) {
        asm volatile("s_waitcnt vmcnt(4)" ::: "memory");  // stage(t) landed; t+1 in flight
        __builtin_amdgcn_s_barrier();
        __builtin_amdgcn_sched_barrier(0);
        stage((t + 2) * 32, (t + 2) % 3);
        mfma_step(t % 3);
    }
    // ---- t = NS-2 (no stage issue) ----
    asm volatile("s_waitcnt vmcnt(4)" ::: "memory");
    __builtin_amdgcn_s_barrier();
    __builtin_amdgcn_sched_barrier(0);
    mfma_step((NS - 2) % 3);
    // ---- t = NS-1 (drain) ----
    asm volatile("s_waitcnt vmcnt(0)" ::: "memory");
    __builtin_amdgcn_s_barrier();
    __builtin_amdgcn_sched_barrier(0);
    mfma_step((NS - 1) % 3);

    // C/D layout (m89): col = lane&15, row = (lane>>4)*4 + reg
    #pragma unroll
    for (int i = 0; i < 4; ++i)
        #pragma unroll
        for (int j = 0; j < 4; ++j)
            #pragma unroll
            for (int r = 0; r < 4; ++r) {
                int row = m0 + wm * 64 + i * 16 + lhi * 4 + r;
                int col = n0 + wn * 64 + j * 16 + l15;
                float v = acc[i][j][r] * cscale;
                if constexpr (C_F32)
                    ((float*)Cp)[(size_t)row * N + col] = v;
                else
                    ((__bf16*)Cp)[(size_t)row * N + col] = (__bf16)v;
            }
}

// QKV projection: grid 768 blocks flat; XCD-swizzled (each XCD: 12 A-panels + 1 weight)
__global__ __launch_bounds__(256) void proj_qkv_kernel(
    const __bf16* __restrict__ act, const __bf16* __restrict__ wc,
    __bf16* __restrict__ oq, __bf16* __restrict__ ok, __bf16* __restrict__ ov)
{
    int lid = blockIdx.x + 8 * blockIdx.y + 256 * blockIdx.z;
    int nid = (lid & 7) * 96 + (lid >> 3);          // bijective: 768 = 8*96
    int z = nid >> 8, rem = nid & 255;
    int m0 = (rem >> 3) * 128, n0 = (rem & 7) * 128;

    const __bf16* A = act + (size_t)z * (MTOT * DMODEL);
    const __bf16* Bt = wc + (size_t)z * (DMODEL * DMODEL);
    __bf16* C; float cs;
    if (z == 0)      { C = oq; cs = SCL2; }
    else if (z == 1) { C = ok; cs = 1.0f; }
    else             { C = ov; cs = 1.0f; }
    gemm_body<false>(A, Bt, C, m0, n0, cs);
}

__global__ __launch_bounds__(256) void proj_out_kernel(
    const __bf16* __restrict__ ctx, const __bf16* __restrict__ woc, float* __restrict__ out)
{
    int lid = blockIdx.x + 8 * blockIdx.y;
    int nid = (lid & 7) * 32 + (lid >> 3);          // bijective: 256 = 8*32
    gemm_body<true>(ctx, woc, out, (nid >> 3) * 128, (nid & 7) * 128, 1.0f);
}

// ================= Flash attention (R16-proven: no online max, 1 sync/tile) ==========
// 512 blocks x 512 threads (8 waves); each wave owns 16 q-rows; block covers 128
// q-rows per staged K/V tile. Straight-line control flow (R8/R10 spill lesson).
// K,V double-buffered; ONE __syncthreads per tile. R15 lesson: no mixed-type counted
// vmcnt rings. R17/R18/R21 lessons: 4-wave blocks / split-K / reg-cached frags all
// null-or-worse — this 8-wave form is the verified optimum of the explored space.
__global__ __launch_bounds__(512, 2) void attn_kernel(
    const __bf16* __restrict__ Qm, const __bf16* __restrict__ Km,
    const __bf16* __restrict__ Vm, __bf16* __restrict__ Om)
{
    constexpr int LDV = 72, LDP = 72;
    __shared__ __bf16 k_sh[2][64 * 64];     // dbuf; glds16, chunk xor (c^(row&7))
    __shared__ __bf16 v_sh[2][64 * LDV];    // dbuf; (d,kv) at d*72 + ((kv+8*(d>>3))&63)
    __shared__ __bf16 p_sh[8][16 * LDP];    // per-wave, rotated on q>>3

    const int tid  = threadIdx.x;
    const int wave = tid >> 6, lane = tid & 63;
    const int l15 = lane & 15, lhi = lane >> 4;

    int old = blockIdx.x + 16 * blockIdx.y;
    int nid = (old & 7) * 64 + (old >> 3);           // bijective: 512 = 8*64
    const int bh = nid >> 4, x = nid & 15;
    const int p = ((bh >> 1) & 1) ? 15 - x : x;      // 128-row q-tile depth, balanced
    const int q0 = p * 128;
    const int b = bh >> 4, h = bh & 15;

    const __bf16* Qb = Qm + (size_t)b * SEQ * DMODEL + h * DK;
    const __bf16* Kb = Km + (size_t)b * SEQ * DMODEL + h * DK;
    const __bf16* Vb = Vm + (size_t)b * SEQ * DMODEL + h * DK;

    const int qbase = q0 + wave * 16;

    // Q fragments (A layout: row = lane&15, k = (lane>>4)*8 + j); pre-scaled by SCL2
    bf16x8_t qf[2];
    {
        const __bf16* qp = Qb + (size_t)(qbase + l15) * DMODEL + lhi * 8;
        qf[0] = *(const bf16x8_t*)qp;
        qf[1] = *(const bf16x8_t*)(qp + 32);
    }
    bf16x8_t onesf;
    #pragma unroll
    for (int j = 0; j < 8; ++j) onesf[j] = (__bf16)1.0f;

    f32x4_t acc[4] = {};
    f32x4_t acc_l = {};   // row-sum accumulator via ones-MFMA (replicated over l15)

    // ---- staging helpers (512 threads: one 16B K-chunk / one bf16x8 V-chunk each) ----
    const int vrow = tid >> 3, vgrp = tid & 7;
    bf16x8_t vreg;

    auto stageK = [&](int kv0, int buf) {
        int row = tid >> 3, c = (tid & 7) ^ (row & 7);
        glds16(Kb + (size_t)(kv0 + row) * DMODEL + c * 8,
               (char*)k_sh[buf] + (size_t)tid * 16);
    };
    auto loadV = [&](int kv0) {
        vreg = *(const bf16x8_t*)(Vb + (size_t)(kv0 + vrow) * DMODEL + vgrp * 8);
    };
    auto writeV = [&](int buf) {
        int sh = (vrow + vgrp * 8) & 63;
        #pragma unroll
        for (int j = 0; j < 8; ++j) v_sh[buf][(vgrp * 8 + j) * LDV + sh] = vreg[j];
    };

    auto body = [&](auto needmask_c, int kv0, int cur) {
        constexpr bool NEEDMASK = decltype(needmask_c)::value;
        const __bf16* ks_buf = k_sh[cur];
        const __bf16* vs_buf = v_sh[cur];

        // ---- S = Q K^T (exp2 domain via pre-scaled Q) ----
        f32x4_t sf[4] = {};
        __builtin_amdgcn_s_setprio(1);
        #pragma unroll
        for (int ks = 0; ks < 2; ++ks)
            #pragma unroll
            for (int n = 0; n < 4; ++n) {
                int row = n * 16 + l15;
                bf16x8_t kf = *(const bf16x8_t*)(ks_buf + row * 64 + (((ks * 4 + lhi) ^ (row & 7)) * 8));
                sf[n] = MFMA16(qf[ks], kf, sf[n]);
            }
        __builtin_amdgcn_s_setprio(0);

        // ---- P = exp2(S) with diag mask; write rotated to per-wave LDS ----
        const int qrow_base = qbase + lhi * 4;
        #pragma unroll
        for (int r = 0; r < 4; ++r)
            #pragma unroll
            for (int n = 0; n < 4; ++n) {
                float sv = sf[n][r];
                if constexpr (NEEDMASK)
                    if (kv0 + n * 16 + l15 > qrow_base + r) sv = -1.0e30f;
                p_sh[wave][(lhi * 4 + r) * LDP + ((n * 16 + l15 + ((lhi >> 1) << 3)) & 63)]
                    = (__bf16)exp2_fast(sv);
            }

        // ---- ctx += P V ; l += P * ones (via MFMA) ----
        __builtin_amdgcn_s_setprio(1);
        #pragma unroll
        for (int ks = 0; ks < 2; ++ks) {
            bf16x8_t pa = *(const bf16x8_t*)(
                &p_sh[wave][l15 * LDP + ((ks * 32 + lhi * 8 + ((l15 >> 3) << 3)) & 63)]);
            acc_l = MFMA16(pa, onesf, acc_l);
            #pragma unroll
            for (int n = 0; n < 4; ++n) {
                int d = n * 16 + l15;
                int rot = (ks * 32 + lhi * 8 + ((d >> 3) << 3)) & 63;
                bf16x8_t vf = *(const bf16x8_t*)(vs_buf + d * LDV + rot);
                acc[n] = MFMA16(pa, vf, acc[n]);
            }
        }
        __builtin_amdgcn_s_setprio(0);
    };

    // ---- prologue: stage tile 0 into buf 0 ----
    stageK(0, 0);
    loadV(0);
    writeV(0);           // compiler waits vmcnt for vreg
    __syncthreads();     // K glds + V ds_writes drained

    // ---- main loop: tiles 0..2p-1 provably unmasked for ALL waves; 1 barrier/tile ----
    for (int t = 0; t < 2 * p; ++t) {
        stageK((t + 1) * 64, (t & 1) ^ 1);   // async prefetch into other K buf
        loadV((t + 1) * 64);                 // global->reg, waits during body
        body(std::integral_constant<bool, false>{}, t * 64, t & 1);
        writeV((t & 1) ^ 1);                 // other V buf; no reader this tile
        __syncthreads();                     // drains everything; swap
    }
    // ---- diagonal tile 2p (prefetch 2p+1), then final tile 2p+1 ----
    {
        const int t = 2 * p;
        stageK((t + 1) * 64, (t & 1) ^ 1);
        loadV((t + 1) * 64);
        body(std::integral_constant<bool, true>{}, t * 64, t & 1);
        writeV((t & 1) ^ 1);
        __syncthreads();
        body(std::integral_constant<bool, true>{}, (t + 1) * 64, (t + 1) & 1);
    }

    // ---- epilogue: acc_l holds full row sums (replicated over l15) ----
    __bf16* Ob = Om + (size_t)b * SEQ * DMODEL + h * DK;
    #pragma unroll
    for (int n = 0; n < 4; ++n)
        #pragma unroll
        for (int r = 0; r < 4; ++r) {
            int row = qbase + lhi * 4 + r;
            Ob[(size_t)row * DMODEL + n * 16 + l15] = (__bf16)(acc[n][r] / acc_l[r]);
        }
}

// ================= launch ============================================================
extern "C" void kernel_launch(void* const* d_in, const int* in_sizes, int n_in,
                              void* d_out, int out_size, void* d_ws, size_t ws_size,
                              hipStream_t stream)
{
    const float* q  = (const float*)d_in[0];
    const float* k  = (const float*)d_in[1];
    const float* v  = (const float*)d_in[2];
    const float* wq = (const float*)d_in[4];
    const float* wk = (const float*)d_in[5];
    const float* wv = (const float*)d_in[6];
    const float* wo = (const float*)d_in[7];
    float* out = (float*)d_out;

    const size_t mat = (size_t)MTOT * DMODEL;        // 4M elems
    __bf16* Qw = (__bf16*)d_ws;                      // 8 MB each
    __bf16* Kw = Qw + mat;
    __bf16* Vw = Kw + mat;
    __bf16* Cw = Vw + mat;
    __bf16* Wc = Cw + mat;                           // 4 x 2MB bf16 weights
    __bf16* Aw = Wc + 4 * (size_t)(DMODEL * DMODEL); // 3 x 8MB bf16 activations

    dim3 blk(256);
    cvt_all_kernel<<<dim3(2048, 7), blk, 0, stream>>>(q, k, v, wq, wk, wv, wo, Aw, Wc);
    proj_qkv_kernel<<<dim3(8, 32, 3), blk, 0, stream>>>(Aw, Wc, Qw, Kw, Vw);
    attn_kernel<<<dim3(16, 32), dim3(512), 0, stream>>>(Qw, Kw, Vw, Cw);
    proj_out_kernel<<<dim3(8, 32), blk, 0, stream>>>(Cw, Wc + 3 * DMODEL * DMODEL, out);
}